// Round 10
// baseline (209.508 us; speedup 1.0000x reference)
//
#include <hip/hip_runtime.h>
#include <cstdint>
#include <cstddef>

#define NNODES 100000
#define NEDGES 1600000
#define NWIN 100
#define WIN_NODES 1000                   // NNODES / NWIN
#define WCAP 17408                       // per-window cap (mean 16000, sigma~126, +11 sigma)
#define WSTR 16                          // wcur stride (ints) -> one cache line per window

#define GM_ROWS 128
#define APAD 72
#define GEMM_BLOCKS ((NNODES + GM_ROWS - 1) / GM_ROWS)   // 782
#define BUCKET_BLOCKS 512
#define BCHUNK ((NEDGES + BUCKET_BLOCKS - 1) / BUCKET_BLOCKS)  // 3125
#define MEGA_BLOCKS (GEMM_BLOCKS + BUCKET_BLOCKS)        // 1294

typedef __attribute__((ext_vector_type(8))) short bf16x8;
typedef __attribute__((ext_vector_type(4))) float f32x4;
typedef __attribute__((ext_vector_type(4))) unsigned short ushort4v;
typedef __attribute__((ext_vector_type(8))) unsigned short ushort8v;

__device__ inline unsigned short f2bf(float f) {
    union { float f; unsigned u; } v; v.f = f;
    unsigned r = v.u + 0x7FFFu + ((v.u >> 16) & 1u);   // RNE
    return (unsigned short)(r >> 16);
}
__device__ inline float bf2f(unsigned short b) {
    union { unsigned u; float f; } v; v.u = ((unsigned)b) << 16; return v.f;
}
__device__ inline void bfpair(unsigned u, float& lo, float& hi) {
    union { unsigned x; float f; } a, b;
    a.x = u << 16; b.x = u & 0xffff0000u;
    lo = a.f; hi = b.f;
}

// ---------------- W1 convert+transpose (+ wcur zero) ----------------

__global__ __launch_bounds__(256) void convW(const float* __restrict__ W,
                                             unsigned short* __restrict__ Wt,
                                             int* __restrict__ wcur) {
    if (blockIdx.x == 0 && threadIdx.x < NWIN) wcur[threadIdx.x * WSTR] = 0;
    int i = blockIdx.x * 256 + threadIdx.x;
    if (i < 512 * 64) {
        int k = i >> 6, n = i & 63;
        Wt[n * 512 + k] = f2bf(W[i]);
    }
}

// ---------------- MEGA kernel: GEMM role + edge-bucketing role (unchanged, r9) ----------------

__global__ __launch_bounds__(256) void mega_gemm_bucket(
        const float* __restrict__ A,            // [M,512] x
        const unsigned short* __restrict__ Wt,  // [64][512] bf16
        unsigned short* __restrict__ Hs,        // [M,64] bf16 UNSCALED out
        const int* __restrict__ src, const int* __restrict__ dst,
        unsigned* __restrict__ stage,
        int* __restrict__ wcur, int M, int E) {
    __shared__ __align__(16) unsigned char smem[18432 + 9216];

    long long b = blockIdx.x;
    int g0 = (int)((b * GEMM_BLOCKS) / MEGA_BLOCKS);
    int g1 = (int)(((b + 1) * GEMM_BLOCKS) / MEGA_BLOCKS);

    if (g1 > g0) {
        typedef unsigned short RowA[APAD];
        RowA* As = (RowA*)smem;
        RowA* Bs = (RowA*)(smem + 18432);
        const int tid = threadIdx.x;
        const int wid = tid >> 6;
        const int lane = tid & 63;
        const int bm = g0 * GM_ROWS;

        f32x4 acc[2][4];
#pragma unroll
        for (int i = 0; i < 2; i++)
#pragma unroll
            for (int j = 0; j < 4; j++) acc[i][j] = (f32x4){0.f, 0.f, 0.f, 0.f};

        const int ar = tid >> 4;
        const int ac4 = tid & 15;
        const int lm = lane & 15;
        const int lk = (lane >> 4) * 8;

        float4 aR0[8], aR1[8];
        ushort8v bR0[2], bR1[2];

        auto LOADA = [&](float4 (&aRx)[8], ushort8v (&bRx)[2], int k0) {
#pragma unroll
            for (int p = 0; p < 8; p++) {
                int row = bm + p * 16 + ar;
                if (row < M) aRx[p] = *(const float4*)&A[(size_t)row * 512 + k0 + ac4 * 4];
                else         aRx[p] = make_float4(0.f, 0.f, 0.f, 0.f);
            }
#pragma unroll
            for (int p = 0; p < 2; p++) {
                int c = p * 256 + tid;
                int n = c >> 3, kc = c & 7;
                bRx[p] = *(const ushort8v*)&Wt[(size_t)n * 512 + k0 + kc * 8];
            }
        };

        auto TILE = [&](float4 (&aRx)[8], ushort8v (&bRx)[2], int k0) {
#pragma unroll
            for (int p = 0; p < 8; p++) {
                int r = p * 16 + ar;
                unsigned lo, hi;
                asm("v_cvt_pk_bf16_f32 %0, %1, %2" : "=v"(lo) : "v"(aRx[p].x), "v"(aRx[p].y));
                asm("v_cvt_pk_bf16_f32 %0, %1, %2" : "=v"(hi) : "v"(aRx[p].z), "v"(aRx[p].w));
                uint2 u; u.x = lo; u.y = hi;
                *(uint2*)&As[r][ac4 * 4] = u;
            }
#pragma unroll
            for (int p = 0; p < 2; p++) {
                int c = p * 256 + tid;
                int n = c >> 3, kc = c & 7;
                *(ushort8v*)&Bs[n][kc * 8] = bRx[p];
            }
            __syncthreads();

            if (k0 + 128 < 512) LOADA(aRx, bRx, k0 + 128);

            bf16x8 a[2][2], bb[4][2];
#pragma unroll
            for (int rf = 0; rf < 2; rf++)
#pragma unroll
                for (int kf = 0; kf < 2; kf++)
                    a[rf][kf] = *(const bf16x8*)&As[wid * 32 + rf * 16 + lm][kf * 32 + lk];
#pragma unroll
            for (int cf = 0; cf < 4; cf++)
#pragma unroll
                for (int kf = 0; kf < 2; kf++)
                    bb[cf][kf] = *(const bf16x8*)&Bs[cf * 16 + lm][kf * 32 + lk];

            __builtin_amdgcn_s_setprio(1);
#pragma unroll
            for (int kf = 0; kf < 2; kf++)
#pragma unroll
                for (int rf = 0; rf < 2; rf++)
#pragma unroll
                    for (int cf = 0; cf < 4; cf++)
                        acc[rf][cf] = __builtin_amdgcn_mfma_f32_16x16x32_bf16(
                            a[rf][kf], bb[cf][kf], acc[rf][cf], 0, 0, 0);
            __builtin_amdgcn_s_setprio(0);
            __syncthreads();
        };

        LOADA(aR0, bR0, 0);
        LOADA(aR1, bR1, 64);
        for (int tp = 0; tp < 4; tp++) {
            TILE(aR0, bR0, tp * 128);
            TILE(aR1, bR1, tp * 128 + 64);
        }

#pragma unroll
        for (int rf = 0; rf < 2; rf++) {
#pragma unroll
            for (int j = 0; j < 4; j++) {
                int row = bm + wid * 32 + rf * 16 + (lane >> 4) * 4 + j;
                if (row < M) {
#pragma unroll
                    for (int cf = 0; cf < 4; cf++)
                        Hs[(size_t)row * 64 + cf * 16 + lm] = f2bf(acc[rf][cf][j]);
                }
            }
        }
    } else {
        int bi = (int)(b - g0);
        int* cnt  = (int*)smem;
        int* lcur = cnt + NWIN;
        const int tid = threadIdx.x;
        int e0 = bi * BCHUNK;
        int e1 = e0 + BCHUNK; if (e1 > E) e1 = E;

        for (int i = tid; i < NWIN; i += 256) cnt[i] = 0;
        __syncthreads();
        for (int e = e0 + tid; e < e1; e += 256) {
            int d = dst[e];
            atomicAdd(&cnt[d / WIN_NODES], 1);
        }
        __syncthreads();
        for (int i = tid; i < NWIN; i += 256)
            lcur[i] = atomicAdd(&wcur[i * WSTR], cnt[i]);
        __syncthreads();
        for (int e = e0 + tid; e < e1; e += 256) {
            int d = dst[e], s = src[e];
            int w = d / WIN_NODES;
            int pos = atomicAdd(&lcur[w], 1);
            if (pos < WCAP)
                stage[(size_t)w * WCAP + pos] =
                    ((unsigned)(d - w * WIN_NODES) << 17) | (unsigned)s;
        }
    }
}

// ---------------- csr_window: hist + scan + dinv + rowstart + fill + Hs1 pre-scale ----------------

__global__ __launch_bounds__(256) void csr_window(
        const unsigned* __restrict__ stage,
        const int* __restrict__ wcur,
        int* __restrict__ rowstart,   // [NNODES+1]
        float* __restrict__ dinv,     // [NNODES]
        int* __restrict__ csr,
        unsigned* __restrict__ H32) { // Hs1 as dwords, scaled in place by dinv[row]
    __shared__ int cnt[WIN_NODES];
    __shared__ float dlds[WIN_NODES];
    __shared__ int red[256];
    const int w = blockIdx.x;
    const int t = threadIdx.x;
    const int wb = w * WIN_NODES;
    const size_t sb = (size_t)w * WCAP;

    int v = (t < w) ? min(wcur[t * WSTR], WCAP) : 0;
    red[t] = v;
    __syncthreads();
#pragma unroll
    for (int off = 128; off > 0; off >>= 1) {
        if (t < off) red[t] += red[t + off];
        __syncthreads();
    }
    int woff = red[0];
    int n_w = min(wcur[w * WSTR], WCAP);
    __syncthreads();

    for (int i = t; i < WIN_NODES; i += 256) cnt[i] = 0;
    __syncthreads();
    for (int i = t; i < n_w; i += 256)
        atomicAdd(&cnt[stage[sb + i] >> 17], 1);
    __syncthreads();

    int c0 = 0, c1 = 0, c2 = 0, c3 = 0, psum = 0;
    if (t < 250) {
        c0 = cnt[4 * t]; c1 = cnt[4 * t + 1]; c2 = cnt[4 * t + 2]; c3 = cnt[4 * t + 3];
        psum = c0 + c1 + c2 + c3;
    }
    red[t] = psum;
    __syncthreads();
#pragma unroll
    for (int off = 1; off < 256; off <<= 1) {
        int tv = (t >= off) ? red[t - off] : 0;
        __syncthreads();
        red[t] += tv;
        __syncthreads();
    }
    int excl = red[t] - psum;
    if (t < 250) {
        int running = woff + excl;
        int idx = 4 * t;
        float d0 = rsqrtf((float)c0 + 1.f), d1 = rsqrtf((float)c1 + 1.f);
        float d2 = rsqrtf((float)c2 + 1.f), d3 = rsqrtf((float)c3 + 1.f);
        rowstart[wb + idx] = running; dinv[wb + idx] = d0; dlds[idx] = d0;
        cnt[idx] = running; running += c0;
        rowstart[wb + idx + 1] = running; dinv[wb + idx + 1] = d1; dlds[idx + 1] = d1;
        cnt[idx + 1] = running; running += c1;
        rowstart[wb + idx + 2] = running; dinv[wb + idx + 2] = d2; dlds[idx + 2] = d2;
        cnt[idx + 2] = running; running += c2;
        rowstart[wb + idx + 3] = running; dinv[wb + idx + 3] = d3; dlds[idx + 3] = d3;
        cnt[idx + 3] = running;
    }
    if (w == NWIN - 1 && t == 0) rowstart[NNODES] = woff + n_w;
    __syncthreads();

    // drain: fill csr via LDS cursors
    for (int i = t; i < n_w; i += 256) {
        unsigned p = stage[sb + i];
        int dl = (int)(p >> 17);
        int s  = (int)(p & 0x1FFFFu);
        int pos = atomicAdd(&cnt[dl], 1);
        csr[pos] = s;
    }

    // pre-scale this window's Hs1 rows by dinv[row] (bf16 in place; 32 dwords/row)
    for (int i = t; i < WIN_NODES * 32; i += 256) {
        int dl = i >> 5;
        float dd = dlds[dl];
        size_t idx = (size_t)(wb + dl) * 32 + (i & 31);
        unsigned u = H32[idx];
        float lo, hi;
        bfpair(u, lo, hi);
        H32[idx] = (unsigned)f2bf(lo * dd) | ((unsigned)f2bf(hi * dd) << 16);
    }
}

// ---------------- gather64 + fused 64->16 transform (pre-scaled input, 16 lanes/row) ----------------
// agg1 = dinv[d]*(Hs[d] + sum Hs[s]) + b1; r = relu(agg1); Hs2 = bf16((r@W2)*dinv[d])

__global__ __launch_bounds__(256) void gather64_l2(
        const int* __restrict__ rowstart, const int* __restrict__ csr,
        const float* __restrict__ dinv,
        const unsigned short* __restrict__ Hs1,   // [M,64] bf16 PRE-SCALED
        const float* __restrict__ b1,
        const float* __restrict__ W2,             // [64,16]
        unsigned short* __restrict__ Hs2,         // [M,16] bf16
        int M) {
    __shared__ float Ws2[64 * 16];
    __shared__ float b1s[64];
    __shared__ float srow[16][68];
    for (int i = threadIdx.x; i < 64 * 16; i += 256) Ws2[i] = W2[i];
    if (threadIdx.x < 64) b1s[threadIdx.x] = b1[threadIdx.x];
    __syncthreads();

    const int r = threadIdx.x >> 4;    // local row 0..15
    const int lf = threadIdx.x & 15;   // owns features [4lf, 4lf+4)
    const int row = blockIdx.x * 16 + r;
    const bool rok = (row < M);

    float a0 = 0.f, a1 = 0.f, a2 = 0.f, a3 = 0.f;
    if (rok) {
        const uint2* H8 = (const uint2*)Hs1;   // 8B = 4 bf16
        int e0 = rowstart[row], e1 = rowstart[row + 1];
        uint2 u = H8[(size_t)row * 16 + lf];   // self term (pre-scaled)
        bfpair(u.x, a0, a1); bfpair(u.y, a2, a3);
        int e = e0;
        for (; e + 7 < e1; e += 8) {
            int s0 = csr[e], s1 = csr[e+1], s2 = csr[e+2], s3 = csr[e+3];
            int s4 = csr[e+4], s5 = csr[e+5], s6 = csr[e+6], s7 = csr[e+7];
            uint2 u0 = H8[(size_t)s0 * 16 + lf];
            uint2 u1 = H8[(size_t)s1 * 16 + lf];
            uint2 u2 = H8[(size_t)s2 * 16 + lf];
            uint2 u3 = H8[(size_t)s3 * 16 + lf];
            uint2 u4 = H8[(size_t)s4 * 16 + lf];
            uint2 u5 = H8[(size_t)s5 * 16 + lf];
            uint2 u6 = H8[(size_t)s6 * 16 + lf];
            uint2 u7 = H8[(size_t)s7 * 16 + lf];
            float x0, x1;
            bfpair(u0.x, x0, x1); a0 += x0; a1 += x1; bfpair(u0.y, x0, x1); a2 += x0; a3 += x1;
            bfpair(u1.x, x0, x1); a0 += x0; a1 += x1; bfpair(u1.y, x0, x1); a2 += x0; a3 += x1;
            bfpair(u2.x, x0, x1); a0 += x0; a1 += x1; bfpair(u2.y, x0, x1); a2 += x0; a3 += x1;
            bfpair(u3.x, x0, x1); a0 += x0; a1 += x1; bfpair(u3.y, x0, x1); a2 += x0; a3 += x1;
            bfpair(u4.x, x0, x1); a0 += x0; a1 += x1; bfpair(u4.y, x0, x1); a2 += x0; a3 += x1;
            bfpair(u5.x, x0, x1); a0 += x0; a1 += x1; bfpair(u5.y, x0, x1); a2 += x0; a3 += x1;
            bfpair(u6.x, x0, x1); a0 += x0; a1 += x1; bfpair(u6.y, x0, x1); a2 += x0; a3 += x1;
            bfpair(u7.x, x0, x1); a0 += x0; a1 += x1; bfpair(u7.y, x0, x1); a2 += x0; a3 += x1;
        }
        for (; e < e1; e++) {
            uint2 ue = H8[(size_t)csr[e] * 16 + lf];
            float x0, x1;
            bfpair(ue.x, x0, x1); a0 += x0; a1 += x1;
            bfpair(ue.y, x0, x1); a2 += x0; a3 += x1;
        }
        float dd = dinv[row];
        a0 = fmaxf(a0 * dd + b1s[4 * lf + 0], 0.f);
        a1 = fmaxf(a1 * dd + b1s[4 * lf + 1], 0.f);
        a2 = fmaxf(a2 * dd + b1s[4 * lf + 2], 0.f);
        a3 = fmaxf(a3 * dd + b1s[4 * lf + 3], 0.f);
    }
    float4 t4; t4.x = a0; t4.y = a1; t4.z = a2; t4.w = a3;
    *(float4*)&srow[r][4 * lf] = t4;
    __syncthreads();

    // 64->16 matvec: thread (r,lf) computes output feature lf
    if (rok) {
        float acc = 0.f;
#pragma unroll
        for (int k4 = 0; k4 < 16; k4++) {
            float4 s4 = *(const float4*)&srow[r][k4 * 4];
            acc += s4.x * Ws2[(k4 * 4 + 0) * 16 + lf];
            acc += s4.y * Ws2[(k4 * 4 + 1) * 16 + lf];
            acc += s4.z * Ws2[(k4 * 4 + 2) * 16 + lf];
            acc += s4.w * Ws2[(k4 * 4 + 3) * 16 + lf];
        }
        acc *= dinv[row];
        float hi = __shfl_down(acc, 1, 64);
        if ((lf & 1) == 0) {
            unsigned p = (unsigned)f2bf(acc) | ((unsigned)f2bf(hi) << 16);
            ((unsigned*)Hs2)[(size_t)row * 8 + (lf >> 1)] = p;
        }
    }
}

// ---------------- layer-2 aggregation (4 lanes/row, 8B loads, unroll 8) ----------------
// r2s = bf16( relu( dinv*(Hs2[d]+sum Hs2[s]) + b2 ) * dinv )

__global__ __launch_bounds__(256) void gather16_agg(
        const int* __restrict__ rowstart, const int* __restrict__ csr,
        const float* __restrict__ dinv,
        const unsigned short* __restrict__ Hs,   // [M,16] bf16 pre-scaled
        const float* __restrict__ bias,          // [16]
        unsigned short* __restrict__ outp,       // [M,16] bf16
        int M) {
    __shared__ float bs[16];
    if (threadIdx.x < 16) bs[threadIdx.x] = bias[threadIdx.x];
    __syncthreads();

    const int r = threadIdx.x >> 2;    // 0..63
    const int lf = threadIdx.x & 3;    // owns features [4lf, 4lf+4)
    const int row = blockIdx.x * 64 + r;
    if (row >= M) return;

    const unsigned long long* H8 = (const unsigned long long*)Hs;
    int e0 = rowstart[row], e1 = rowstart[row + 1];
    unsigned long long u = H8[(size_t)row * 4 + lf];
    float a0, a1, a2, a3;
    bfpair((unsigned)u, a0, a1); bfpair((unsigned)(u >> 32), a2, a3);
    int e = e0;
    for (; e + 7 < e1; e += 8) {
        int s0 = csr[e], s1 = csr[e+1], s2 = csr[e+2], s3 = csr[e+3];
        int s4 = csr[e+4], s5 = csr[e+5], s6 = csr[e+6], s7 = csr[e+7];
        unsigned long long u0 = H8[(size_t)s0 * 4 + lf];
        unsigned long long u1 = H8[(size_t)s1 * 4 + lf];
        unsigned long long u2 = H8[(size_t)s2 * 4 + lf];
        unsigned long long u3 = H8[(size_t)s3 * 4 + lf];
        unsigned long long u4 = H8[(size_t)s4 * 4 + lf];
        unsigned long long u5 = H8[(size_t)s5 * 4 + lf];
        unsigned long long u6 = H8[(size_t)s6 * 4 + lf];
        unsigned long long u7 = H8[(size_t)s7 * 4 + lf];
        float x0, x1;
        bfpair((unsigned)u0, x0, x1); a0 += x0; a1 += x1;
        bfpair((unsigned)(u0 >> 32), x0, x1); a2 += x0; a3 += x1;
        bfpair((unsigned)u1, x0, x1); a0 += x0; a1 += x1;
        bfpair((unsigned)(u1 >> 32), x0, x1); a2 += x0; a3 += x1;
        bfpair((unsigned)u2, x0, x1); a0 += x0; a1 += x1;
        bfpair((unsigned)(u2 >> 32), x0, x1); a2 += x0; a3 += x1;
        bfpair((unsigned)u3, x0, x1); a0 += x0; a1 += x1;
        bfpair((unsigned)(u3 >> 32), x0, x1); a2 += x0; a3 += x1;
        bfpair((unsigned)u4, x0, x1); a0 += x0; a1 += x1;
        bfpair((unsigned)(u4 >> 32), x0, x1); a2 += x0; a3 += x1;
        bfpair((unsigned)u5, x0, x1); a0 += x0; a1 += x1;
        bfpair((unsigned)(u5 >> 32), x0, x1); a2 += x0; a3 += x1;
        bfpair((unsigned)u6, x0, x1); a0 += x0; a1 += x1;
        bfpair((unsigned)(u6 >> 32), x0, x1); a2 += x0; a3 += x1;
        bfpair((unsigned)u7, x0, x1); a0 += x0; a1 += x1;
        bfpair((unsigned)(u7 >> 32), x0, x1); a2 += x0; a3 += x1;
    }
    for (; e < e1; e++) {
        unsigned long long ue = H8[(size_t)csr[e] * 4 + lf];
        float x0, x1;
        bfpair((unsigned)ue, x0, x1); a0 += x0; a1 += x1;
        bfpair((unsigned)(ue >> 32), x0, x1); a2 += x0; a3 += x1;
    }

    float dd = dinv[row];
    a0 = fmaxf(a0 * dd + bs[4 * lf + 0], 0.f) * dd;
    a1 = fmaxf(a1 * dd + bs[4 * lf + 1], 0.f) * dd;
    a2 = fmaxf(a2 * dd + bs[4 * lf + 2], 0.f) * dd;
    a3 = fmaxf(a3 * dd + bs[4 * lf + 3], 0.f) * dd;
    uint2 p;
    p.x = (unsigned)f2bf(a0) | ((unsigned)f2bf(a1) << 16);
    p.y = (unsigned)f2bf(a2) | ((unsigned)f2bf(a3) << 16);
    ((uint2*)outp)[(size_t)row * 4 + lf] = p;
}

// ---------------- layer-3 aggregation + 16->40 matvec + log_softmax ----------------

__global__ __launch_bounds__(256) void gather16_final(
        const int* __restrict__ rowstart, const int* __restrict__ csr,
        const float* __restrict__ dinv,
        const unsigned short* __restrict__ r2s,   // [M,16] bf16 pre-scaled
        const float* __restrict__ W3,
        const float* __restrict__ b3,
        float* __restrict__ out,
        int M) {
    __shared__ float Ws3[16 * 40];
    __shared__ float bs3[40];
    __shared__ float srow[64][20];
    __shared__ float orow[64 * 40];
    for (int i = threadIdx.x; i < 16 * 40; i += 256) Ws3[i] = W3[i];
    if (threadIdx.x < 40) bs3[threadIdx.x] = b3[threadIdx.x];

    const int r = threadIdx.x >> 2;    // 0..63
    const int lf = threadIdx.x & 3;
    const int row = blockIdx.x * 64 + r;
    const bool rok = (row < M);

    float a0 = 0.f, a1 = 0.f, a2 = 0.f, a3 = 0.f;
    if (rok) {
        const unsigned long long* H8 = (const unsigned long long*)r2s;
        int e0 = rowstart[row], e1 = rowstart[row + 1];
        unsigned long long u = H8[(size_t)row * 4 + lf];
        bfpair((unsigned)u, a0, a1); bfpair((unsigned)(u >> 32), a2, a3);
        int e = e0;
        for (; e + 7 < e1; e += 8) {
            int s0 = csr[e], s1 = csr[e+1], s2 = csr[e+2], s3 = csr[e+3];
            int s4 = csr[e+4], s5 = csr[e+5], s6 = csr[e+6], s7 = csr[e+7];
            unsigned long long u0 = H8[(size_t)s0 * 4 + lf];
            unsigned long long u1 = H8[(size_t)s1 * 4 + lf];
            unsigned long long u2 = H8[(size_t)s2 * 4 + lf];
            unsigned long long u3 = H8[(size_t)s3 * 4 + lf];
            unsigned long long u4 = H8[(size_t)s4 * 4 + lf];
            unsigned long long u5 = H8[(size_t)s5 * 4 + lf];
            unsigned long long u6 = H8[(size_t)s6 * 4 + lf];
            unsigned long long u7 = H8[(size_t)s7 * 4 + lf];
            float x0, x1;
            bfpair((unsigned)u0, x0, x1); a0 += x0; a1 += x1;
            bfpair((unsigned)(u0 >> 32), x0, x1); a2 += x0; a3 += x1;
            bfpair((unsigned)u1, x0, x1); a0 += x0; a1 += x1;
            bfpair((unsigned)(u1 >> 32), x0, x1); a2 += x0; a3 += x1;
            bfpair((unsigned)u2, x0, x1); a0 += x0; a1 += x1;
            bfpair((unsigned)(u2 >> 32), x0, x1); a2 += x0; a3 += x1;
            bfpair((unsigned)u3, x0, x1); a0 += x0; a1 += x1;
            bfpair((unsigned)(u3 >> 32), x0, x1); a2 += x0; a3 += x1;
            bfpair((unsigned)u4, x0, x1); a0 += x0; a1 += x1;
            bfpair((unsigned)(u4 >> 32), x0, x1); a2 += x0; a3 += x1;
            bfpair((unsigned)u5, x0, x1); a0 += x0; a1 += x1;
            bfpair((unsigned)(u5 >> 32), x0, x1); a2 += x0; a3 += x1;
            bfpair((unsigned)u6, x0, x1); a0 += x0; a1 += x1;
            bfpair((unsigned)(u6 >> 32), x0, x1); a2 += x0; a3 += x1;
            bfpair((unsigned)u7, x0, x1); a0 += x0; a1 += x1;
            bfpair((unsigned)(u7 >> 32), x0, x1); a2 += x0; a3 += x1;
        }
        for (; e < e1; e++) {
            unsigned long long ue = H8[(size_t)csr[e] * 4 + lf];
            float x0, x1;
            bfpair((unsigned)ue, x0, x1); a0 += x0; a1 += x1;
            bfpair((unsigned)(ue >> 32), x0, x1); a2 += x0; a3 += x1;
        }
        float dd = dinv[row];
        a0 *= dd; a1 *= dd; a2 *= dd; a3 *= dd;
    }
    float4 t4; t4.x = a0; t4.y = a1; t4.z = a2; t4.w = a3;
    *(float4*)&srow[r][4 * lf] = t4;
    __syncthreads();

    // matvec: thread (r,lf) computes outputs n = lf + 4q, q=0..9
    float vals[10];
#pragma unroll
    for (int q = 0; q < 10; q++) vals[q] = bs3[lf + 4 * q];
#pragma unroll
    for (int k4 = 0; k4 < 4; k4++) {
        float4 s4 = *(const float4*)&srow[r][k4 * 4];
#pragma unroll
        for (int q = 0; q < 10; q++) {
            int n = lf + 4 * q;
            vals[q] += s4.x * Ws3[(k4 * 4 + 0) * 40 + n];
            vals[q] += s4.y * Ws3[(k4 * 4 + 1) * 40 + n];
            vals[q] += s4.z * Ws3[(k4 * 4 + 2) * 40 + n];
            vals[q] += s4.w * Ws3[(k4 * 4 + 3) * 40 + n];
        }
    }
    float m = vals[0];
#pragma unroll
    for (int q = 1; q < 10; q++) m = fmaxf(m, vals[q]);
#pragma unroll
    for (int off = 1; off < 4; off <<= 1) m = fmaxf(m, __shfl_xor(m, off, 64));
    float s = 0.f;
#pragma unroll
    for (int q = 0; q < 10; q++) s += expf(vals[q] - m);
#pragma unroll
    for (int off = 1; off < 4; off <<= 1) s += __shfl_xor(s, off, 64);
    float ls = logf(s) + m;
#pragma unroll
    for (int q = 0; q < 10; q++) orow[r * 40 + lf + 4 * q] = vals[q] - ls;
    __syncthreads();

    // coalesced store: 64*40 = 2560 floats = 640 float4
    float4* o4 = (float4*)(out + (size_t)blockIdx.x * 64 * 40);
    const float4* s4p = (const float4*)orow;
    for (int i = threadIdx.x; i < 640; i += 256) {
        int rr = (i * 4) / 40;
        if (blockIdx.x * 64 + rr < M) o4[i] = s4p[i];
    }
}

// ---------------- launch ----------------

extern "C" void kernel_launch(void* const* d_in, const int* in_sizes, int n_in,
                              void* d_out, int out_size, void* d_ws, size_t ws_size,
                              hipStream_t stream) {
    const float* x   = (const float*)d_in[0];
    const int*   ei  = (const int*)d_in[1];
    const int*   src = ei;
    const int*   dst = ei + NEDGES;
    const float* W1 = (const float*)d_in[2];
    const float* b1 = (const float*)d_in[3];
    const float* W2 = (const float*)d_in[4];
    const float* b2 = (const float*)d_in[5];
    const float* W3 = (const float*)d_in[6];
    const float* b3 = (const float*)d_in[7];
    float* out = (float*)d_out;

    int* ws_i = (int*)d_ws;
    int* wcur     = ws_i;                        // NWIN*WSTR (padded: 1 line/window)
    int* rowstart = wcur + NWIN * WSTR + 16;     // N+8
    int* csr      = rowstart + NNODES + 8;       // E
    unsigned* stage = (unsigned*)(csr + NEDGES); // NWIN*WCAP
    float* dinv   = (float*)(stage + (size_t)NWIN * WCAP);  // N
    unsigned short* Wt = (unsigned short*)(dinv + NNODES);  // 64*512 bf16
    float* bufA   = (float*)((int*)(Wt + 64 * 512) + 16);
    float* bufB   = bufA + (size_t)NNODES * 64;

    unsigned short* Hs1 = (unsigned short*)bufA;   // [N,64] bf16 (unscaled -> scaled in csr_window)
    unsigned short* Hs2 = (unsigned short*)bufB;   // [N,16] bf16
    unsigned short* r2s = (unsigned short*)bufA;   // [N,16] bf16 (Hs1 dead)

    // --- W1 -> bf16^T + wcur zero ---
    convW<<<(512 * 64 + 255) / 256, 256, 0, stream>>>(W1, Wt, wcur);

    // --- MEGA: GEMM (x@W1, unscaled) overlapped with edge bucketing ---
    mega_gemm_bucket<<<MEGA_BLOCKS, 256, 0, stream>>>(
        x, Wt, Hs1, src, dst, stage, wcur, NNODES, NEDGES);

    // --- CSR finalize + Hs1 pre-scale: one block per window ---
    csr_window<<<NWIN, 256, 0, stream>>>(stage, wcur, rowstart, dinv, csr,
                                         (unsigned*)Hs1);

    // --- layer-1 aggregation + fused 64->16 transform ---
    gather64_l2<<<(NNODES + 15) / 16, 256, 0, stream>>>(
        rowstart, csr, dinv, Hs1, b1, W2, Hs2, NNODES);

    // --- layer-2 aggregation (relu + b2 + pre-scale) ---
    gather16_agg<<<(NNODES + 63) / 64, 256, 0, stream>>>(
        rowstart, csr, dinv, Hs2, b2, r2s, NNODES);

    // --- layer-3 aggregation + 16->40 matvec + log_softmax ---
    gather16_final<<<(NNODES + 63) / 64, 256, 0, stream>>>(
        rowstart, csr, dinv, r2s, W3, b3, out, NNODES);
}